// Round 14
// baseline (1863.408 us; speedup 1.0000x reference)
//
#include <hip/hip_runtime.h>
#include <hip/hip_bf16.h>
#include <math.h>

typedef __bf16 bf16_t;
typedef __bf16 bf16x4 __attribute__((ext_vector_type(4)));
typedef __bf16 bf16x8 __attribute__((ext_vector_type(8)));
typedef float  f32x4  __attribute__((ext_vector_type(4)));
typedef float  f32x16 __attribute__((ext_vector_type(16)));

#define AS1 __attribute__((address_space(1)))
#define AS3 __attribute__((address_space(3)))

__device__ __forceinline__ void gload_lds16(const bf16_t* g, char* l) {
  __builtin_amdgcn_global_load_lds((const AS1 void*)g, (AS3 void*)l, 16, 0, 0);
}

static constexpr int N_ROWS = 8192;
static constexpr int DDIM   = 4096;
static constexpr int KEXP   = 8;
static constexpr int FHID   = 1024;
static constexpr int KD     = 8192;    // inner dim of both GEMMs (2D and K*F)
static constexpr int NKT64  = KD / 64; // 128 packed 64-k tiles
static constexpr int NKT32  = KD / 32; // 256 GEMM k-steps

// ================= packed fragment-major tile format (r10, verified) =================
// Per (256-row block, 64-k tile): 32 KB contiguous.
// A: (R>>7)*16384 + ((k>>4)&3)*4096 + ((R>>5)&3)*1024 + ((k>>3)&1)*512 + (R&31)*16 + (k&7)*2
// B: ((k>>4)&3)*8192 + ((C>>5)&7)*1024 + ((k>>3)&1)*512 + (C&31)*16 + (k&7)*2

// ---------------- routing: weights = softmax(h_mask @ Wr^T + br) ----------------
__global__ __launch_bounds__(256)
void routing_kernel(const float* __restrict__ hm, const float* __restrict__ Wr,
                    const float* __restrict__ br, float* __restrict__ wgt) {
  const int n = blockIdx.x;
  const int t = threadIdx.x;
  const int wid = t >> 6;
  const float4* row = (const float4*)(hm + (size_t)n * DDIM);
  float4 x[4];
#pragma unroll
  for (int j = 0; j < 4; ++j) x[j] = row[t + j * 256];
  __shared__ float red[KEXP][4];
  float part[KEXP];
#pragma unroll
  for (int k = 0; k < KEXP; ++k) {
    const float4* wr = (const float4*)(Wr + (size_t)k * DDIM);
    float s = 0.f;
#pragma unroll
    for (int j = 0; j < 4; ++j) {
      float4 w4 = wr[t + j * 256];
      s += x[j].x * w4.x + x[j].y * w4.y + x[j].z * w4.z + x[j].w * w4.w;
    }
#pragma unroll
    for (int off = 32; off > 0; off >>= 1) s += __shfl_down(s, off);
    part[k] = s;
  }
  if ((t & 63) == 0) {
#pragma unroll
    for (int k = 0; k < KEXP; ++k) red[k][wid] = part[k];
  }
  __syncthreads();
  if (t == 0) {
    float lg[KEXP];
    float mx = -1e30f;
#pragma unroll
    for (int k = 0; k < KEXP; ++k) {
      lg[k] = red[k][0] + red[k][1] + red[k][2] + red[k][3] + br[k];
      mx = fmaxf(mx, lg[k]);
    }
    float sum = 0.f;
#pragma unroll
    for (int k = 0; k < KEXP; ++k) { lg[k] = expf(lg[k] - mx); sum += lg[k]; }
    float inv = 1.f / sum;
#pragma unroll
    for (int k = 0; k < KEXP; ++k) wgt[(size_t)n * KEXP + k] = lg[k] * inv;
  }
}

// ---------------- pack kernels: fp32 source -> bf16 packed tiles (r10) ----------------
__device__ __forceinline__ bf16x4 cvt4(float4 v) {
  bf16x4 o;
  o[0] = (bf16_t)v.x; o[1] = (bf16_t)v.y; o[2] = (bf16_t)v.z; o[3] = (bf16_t)v.w;
  return o;
}

__global__ __launch_bounds__(256)
void pack_cond_kernel(const float* __restrict__ ha, const float* __restrict__ hm,
                      bf16_t* __restrict__ Apk) {
  const int bm = blockIdx.x >> 7, t = blockIdx.x & 127;
  const int tid = threadIdx.x;
  const float* src = (t < 64) ? ha : hm;
  const int cb = (t & 63) * 64;
  __shared__ char pb[32768];
#pragma unroll
  for (int i = 0; i < 16; ++i) {
    int u = i * 256 + tid;
    int r = u >> 4, c = (u & 15) * 4;
    float4 v = *(const float4*)(src + (size_t)(bm * 256 + r) * DDIM + cb + c);
    int off = ((r >> 7) & 1) * 16384 + ((c >> 4) & 3) * 4096 + ((r >> 5) & 3) * 1024
            + ((c >> 3) & 1) * 512 + (r & 31) * 16 + (c & 7) * 2;
    *(bf16x4*)(pb + off) = cvt4(v);
  }
  __syncthreads();
  char* dst = (char*)Apk + (size_t)blockIdx.x * 32768;
#pragma unroll
  for (int i = 0; i < 8; ++i) {
    int off = i * 4096 + tid * 16;
    *(float4*)(dst + off) = *(const float4*)(pb + off);
  }
}

__global__ __launch_bounds__(256)
void pack_w1_kernel(const float* __restrict__ W1, bf16_t* __restrict__ Bpk) {
  const int bn = blockIdx.x >> 7, t = blockIdx.x & 127;
  const int tid = threadIdx.x;
  __shared__ char pb[32768];
#pragma unroll
  for (int i = 0; i < 16; ++i) {
    int u = i * 256 + tid;
    int r = u >> 4, c = (u & 15) * 4;
    float4 v = *(const float4*)(W1 + (size_t)(bn * 256 + r) * KD + t * 64 + c);
    int off = ((c >> 4) & 3) * 8192 + ((r >> 5) & 7) * 1024
            + ((c >> 3) & 1) * 512 + (r & 31) * 16 + (c & 7) * 2;
    *(bf16x4*)(pb + off) = cvt4(v);
  }
  __syncthreads();
  char* dst = (char*)Bpk + (size_t)blockIdx.x * 32768;
#pragma unroll
  for (int i = 0; i < 8; ++i) {
    int off = i * 4096 + tid * 16;
    *(float4*)(dst + off) = *(const float4*)(pb + off);
  }
}

__global__ __launch_bounds__(256)
void pack_w2_kernel(const float* __restrict__ W2, bf16_t* __restrict__ Bpk) {
  const int bn = blockIdx.x >> 7, t = blockIdx.x & 127;
  const int tid = threadIdx.x;
  const int ke = t >> 4, f0 = (t & 15) * 64;
  __shared__ char pb[32768];
#pragma unroll
  for (int i = 0; i < 16; ++i) {
    int u = i * 256 + tid;
    int r = u >> 4, c = (u & 15) * 4;
    float4 v = *(const float4*)(W2 + ((size_t)ke * DDIM + bn * 256 + r) * FHID + f0 + c);
    int off = ((c >> 4) & 3) * 8192 + ((r >> 5) & 7) * 1024
            + ((c >> 3) & 1) * 512 + (r & 31) * 16 + (c & 7) * 2;
    *(bf16x4*)(pb + off) = cvt4(v);
  }
  __syncthreads();
  char* dst = (char*)Bpk + (size_t)blockIdx.x * 32768;
#pragma unroll
  for (int i = 0; i < 8; ++i) {
    int off = i * 4096 + tid * 16;
    *(float4*)(dst + off) = *(const float4*)(pb + off);
  }
}

// ---------------- GEMM v14: v13 structure (2 blocks/CU TLP) + 32x32x16 MFMA --------
// Only change vs v13 (which lifted MfmaUtil 55->61 via independent-block overlap):
// MFMA shape 16x16x32 -> 32x32x16 (ubench 2075 -> 2495 TF, +20% pipe rate; half the
// instruction count -> less issue pressure at VALUBusy 42%). Per-wave 64x64 = 2x2
// tiles of 32x32, acc[2][2] f32x16 = 64 regs (same budget as v13's acc[4][4] f32x4).
// Fragment reads: 8 x ds_read_b128 per K-tile at lane*16 within 1KB blocks (2x512B
// runs, conflict-free; same pattern r10 measured 0 conflicts). Operand/CD lane
// layouts verified end-to-end in r9/r10 (absmax passed).
// Everything else byte-identical to v13 (tripwire-proven): BK=32, 3-buffer ring x
// 24KB, 2 blocks/CU, stage(t+2) 3x1KB/wave, lgkm countdown (4 then 0), vmcnt(3) +
// ONE barrier per k-tile, modular wrap, 16x16-window block remap.
// MODE 1: +b1, exact GELU, *w[n][expert], store bf16 PACKED (Hpk = GEMM2's A)
// MODE 2: + sum_k w[n][k]*b2[k][col], store fp32 row-major (out)
template <int MODE, int NCOLS>
__global__ __launch_bounds__(512, 4)
void gemm_kernel(const bf16_t* __restrict__ Apk, const bf16_t* __restrict__ Bpk,
                 void* __restrict__ Cout, const float* __restrict__ bias,
                 const float* __restrict__ wgt) {
  __shared__ char lds[3 * 24576];        // 72 KB

  const int tid  = threadIdx.x;
  const int wid  = tid >> 6;             // 0..7
  const int lane = tid & 63;
  const int wr   = wid >> 1;             // 0..3  (M quarter, 64 rows)
  const int wc   = wid & 1;              // 0..1  (N half, 64 cols)

  // ---- 2-D concurrency-window block remap (16bm x 16bn window, 4x8 per XCD)
  constexpr int NBN    = NCOLS / 128;    // 64 (GEMM1) or 32 (GEMM2)
  constexpr int NWIN_N = NBN / 16;       // 4 or 2
  const int bid = blockIdx.x;
  const int w   = bid >> 8;
  const int sl  = bid & 255;
  const int xcd = sl & 7;
  const int cu  = sl >> 3;
  const int wm  = w / NWIN_N, wn = w % NWIN_N;
  const int bm  = wm * 16 + ((xcd >> 1) << 2) + (cu & 3);
  const int bn  = wn * 16 + ((xcd & 1) << 3) + (cu >> 2);
  const int arow0 = bm * 256;
  const int bcol0 = bn * 128;

  // ---- staging: 24 x 1KB pieces per K-tile (16 A + 8 B); wave stages A{2w,2w+1}, B{w}
  const char* Abase = (const char*)Apk + (size_t)bm * NKT64 * 32768;
  const char* Bbase = (const char*)Bpk + (size_t)(bn >> 1) * NKT64 * 32768;
  const int pA0 = 2 * wid, pA1 = 2 * wid + 1, qB = wid;
  // A piece p: Rhalf=p>>3, k16=(p>>2)&1, rg=p&3
  const int a0s = (pA0 >> 3) * 16384 + ((pA0 >> 2) & 1) * 4096 + (pA0 & 3) * 1024;
  const int a1s = (pA1 >> 3) * 16384 + ((pA1 >> 2) & 1) * 4096 + (pA1 & 3) * 1024;
  const int a0d = (pA0 >> 3) * 8192 + ((pA0 >> 2) & 1) * 4096 + (pA0 & 3) * 1024;
  const int a1d = (pA1 >> 3) * 8192 + ((pA1 >> 2) & 1) * 4096 + (pA1 & 3) * 1024;
  // B piece q: k16=q>>2, cg=q&3; source col-half = bn&1
  const int bqs = (qB >> 2) * 8192 + ((bn & 1) * 4 + (qB & 3)) * 1024;
  const int bqd = 16384 + (qB >> 2) * 4096 + (qB & 3) * 1024;

  // ---- 32x32 fragment read offsets: lane*16 within 1KB block (conflict-free)
  // LDS A layout: [Rhalf]*8192 + [k16]*4096 + [rg]*1024; wave rows = wr*64 + mi*32
  int aoff[2][2], boff[2][2];
#pragma unroll
  for (int s = 0; s < 2; ++s)
#pragma unroll
    for (int mi = 0; mi < 2; ++mi)
      aoff[s][mi] = (wr >> 1) * 8192 + s * 4096 + ((wr & 1) * 2 + mi) * 1024 + lane * 16;
#pragma unroll
  for (int s = 0; s < 2; ++s)
#pragma unroll
    for (int nj = 0; nj < 2; ++nj)
      boff[s][nj] = 16384 + s * 4096 + (wc * 2 + nj) * 1024 + lane * 16;

  f32x16 acc[2][2];
#pragma unroll
  for (int mi = 0; mi < 2; ++mi)
#pragma unroll
    for (int nj = 0; nj < 2; ++nj)
#pragma unroll
      for (int r = 0; r < 16; ++r) acc[mi][nj][r] = 0.f;

#define SB __builtin_amdgcn_sched_barrier(0);
#define STG3(KT, BUF)                                                            \
  {                                                                              \
    const int kt_ = (KT) & (NKT32 - 1);                                          \
    const size_t t64 = (size_t)(kt_ >> 1) * 32768;                               \
    const int klo = (kt_ & 1) * 2;                                               \
    gload_lds16((const bf16_t*)(Abase + t64 + a0s + klo * 4096 + lane * 16),     \
                (BUF) + a0d);                                                    \
    gload_lds16((const bf16_t*)(Abase + t64 + a1s + klo * 4096 + lane * 16),     \
                (BUF) + a1d);                                                    \
    gload_lds16((const bf16_t*)(Bbase + t64 + bqs + klo * 8192 + lane * 16),     \
                (BUF) + bqd);                                                    \
  }

  // ---- prologue: stage tile 0 -> buf0, tile 1 -> buf1; retire t0; barrier
  STG3(0, lds) STG3(1, lds + 24576) SB
  asm volatile("s_waitcnt vmcnt(3)" ::: "memory");
  SB
  __builtin_amdgcn_s_barrier();
  SB

  char* rb = lds;                 // read buffer  (t   % 3)
  char* mb = lds + 24576;         // next read    (t+1 % 3)
  char* sb = lds + 49152;         // stage target (t+2 % 3)

#pragma unroll 1
  for (int t = 0; t < NKT32; ++t) {
    STG3(t + 2, sb) SB
    bf16x8 a00, a01, b00, b01, a10, a11, b10, b11;
    a00 = *(const bf16x8*)(rb + aoff[0][0]); SB
    a01 = *(const bf16x8*)(rb + aoff[0][1]); SB
    b00 = *(const bf16x8*)(rb + boff[0][0]); SB
    b01 = *(const bf16x8*)(rb + boff[0][1]); SB
    a10 = *(const bf16x8*)(rb + aoff[1][0]); SB
    a11 = *(const bf16x8*)(rb + aoff[1][1]); SB
    b10 = *(const bf16x8*)(rb + boff[1][0]); SB
    b11 = *(const bf16x8*)(rb + boff[1][1]); SB
    __builtin_amdgcn_s_setprio(1);
    asm volatile("s_waitcnt lgkmcnt(4)" ::: "memory"); SB
    acc[0][0] = __builtin_amdgcn_mfma_f32_32x32x16_bf16(a00, b00, acc[0][0], 0, 0, 0);
    acc[0][1] = __builtin_amdgcn_mfma_f32_32x32x16_bf16(a00, b01, acc[0][1], 0, 0, 0);
    acc[1][0] = __builtin_amdgcn_mfma_f32_32x32x16_bf16(a01, b00, acc[1][0], 0, 0, 0);
    acc[1][1] = __builtin_amdgcn_mfma_f32_32x32x16_bf16(a01, b01, acc[1][1], 0, 0, 0);
    SB
    asm volatile("s_waitcnt lgkmcnt(0)" ::: "memory"); SB
    acc[0][0] = __builtin_amdgcn_mfma_f32_32x32x16_bf16(a10, b10, acc[0][0], 0, 0, 0);
    acc[0][1] = __builtin_amdgcn_mfma_f32_32x32x16_bf16(a10, b11, acc[0][1], 0, 0, 0);
    acc[1][0] = __builtin_amdgcn_mfma_f32_32x32x16_bf16(a11, b10, acc[1][0], 0, 0, 0);
    acc[1][1] = __builtin_amdgcn_mfma_f32_32x32x16_bf16(a11, b11, acc[1][1], 0, 0, 0);
    SB
    __builtin_amdgcn_s_setprio(0);
    asm volatile("s_waitcnt vmcnt(3)" ::: "memory");  // t+1's stages retired (publish)
    SB
    __builtin_amdgcn_s_barrier();
    SB
    char* tmp = rb; rb = mb; mb = sb; sb = tmp;
  }
#undef STG3
#undef SB

  // ---- epilogue.  32x32 C/D layout: col = lane&31, row = (r&3)+8*(r>>2)+4*(lane>>5)
  const int rbase = arow0 + wr * 64 + ((lane >> 5) << 2);
  const int cbase = bcol0 + wc * 64 + (lane & 31);

  if constexpr (MODE == 1) {
    // packed H write (r10 A-format): H has 8192 rows x 8192 k
    char* __restrict__ Hc = (char*)Cout;
    const int kexp = bcol0 >> 10;  // expert is block-uniform (128 | 1024)
    float bv[2];
    size_t cpart[2];
#pragma unroll
    for (int nj = 0; nj < 2; ++nj) {
      int c = cbase + nj * 32;
      bv[nj] = bias[c];
      cpart[nj] = (size_t)(c >> 6) * 32768 + ((c >> 4) & 3) * 4096
                + ((c >> 3) & 1) * 512 + (c & 7) * 2;
    }
#pragma unroll
    for (int mi = 0; mi < 2; ++mi)
#pragma unroll
      for (int r = 0; r < 16; ++r) {
        int n = rbase + mi * 32 + (r & 3) + 8 * (r >> 2);
        float wn4 = wgt[(size_t)n * KEXP + kexp];
        size_t npart = (size_t)(n >> 8) * (NKT64 * 32768) + ((n >> 7) & 1) * 16384
                     + ((n >> 5) & 3) * 1024 + (n & 31) * 16;
#pragma unroll
        for (int nj = 0; nj < 2; ++nj) {
          float x = acc[mi][nj][r] + bv[nj];
          float g = 0.5f * x * (1.f + erff(x * 0.70710678118654752f));  // exact GELU
          *(bf16_t*)(Hc + npart + cpart[nj]) = (bf16_t)(g * wn4);
        }
      }
  } else {
    float* __restrict__ O = (float*)Cout;
    float bc[2][KEXP];
#pragma unroll
    for (int nj = 0; nj < 2; ++nj)
#pragma unroll
      for (int k = 0; k < KEXP; ++k)
        bc[nj][k] = bias[(size_t)k * NCOLS + cbase + nj * 32];
#pragma unroll
    for (int mi = 0; mi < 2; ++mi)
#pragma unroll
      for (int r = 0; r < 16; ++r) {
        int n = rbase + mi * 32 + (r & 3) + 8 * (r >> 2);
        const float4* wp = (const float4*)(wgt + (size_t)n * KEXP);
        float4 wa = wp[0], wb = wp[1];
        float w8[KEXP] = {wa.x, wa.y, wa.z, wa.w, wb.x, wb.y, wb.z, wb.w};
#pragma unroll
        for (int nj = 0; nj < 2; ++nj) {
          float s = 0.f;
#pragma unroll
          for (int k = 0; k < KEXP; ++k) s += w8[k] * bc[nj][k];
          O[(size_t)n * NCOLS + cbase + nj * 32] = acc[mi][nj][r] + s;
        }
      }
  }
}

extern "C" void kernel_launch(void* const* d_in, const int* in_sizes, int n_in,
                              void* d_out, int out_size, void* d_ws, size_t ws_size,
                              hipStream_t stream) {
  const float* h_anchor = (const float*)d_in[0];
  const float* h_mask   = (const float*)d_in[1];
  const float* Wr       = (const float*)d_in[2];
  const float* br       = (const float*)d_in[3];
  const float* W1       = (const float*)d_in[4];
  const float* b1       = (const float*)d_in[5];
  const float* W2       = (const float*)d_in[6];
  const float* b2       = (const float*)d_in[7];
  float* out = (float*)d_out;

  char* ws = (char*)d_ws;
  bf16_t* Apk  = (bf16_t*)(ws);                       // packed A    128 MB
  bf16_t* B1pk = (bf16_t*)(ws + ((size_t)128 << 20)); // packed W1   128 MB
  bf16_t* B2pk = (bf16_t*)(ws + ((size_t)256 << 20)); // packed W2    64 MB
  bf16_t* Hpk  = (bf16_t*)(ws + ((size_t)320 << 20)); // packed H1s  128 MB
  float*  wgt  = (float*) (ws + ((size_t)448 << 20)); // [8192][8]   256 KB

  routing_kernel<<<N_ROWS, 256, 0, stream>>>(h_mask, Wr, br, wgt);
  pack_cond_kernel<<<32 * 128, 256, 0, stream>>>(h_anchor, h_mask, Apk);
  pack_w1_kernel<<<32 * 128, 256, 0, stream>>>(W1, B1pk);
  pack_w2_kernel<<<16 * 128, 256, 0, stream>>>(W2, B2pk);

  gemm_kernel<1, 8192><<<(N_ROWS / 256) * (KD / 128), 512, 0, stream>>>(
      Apk, B1pk, (void*)Hpk, b1, wgt);
  gemm_kernel<2, 4096><<<(N_ROWS / 256) * (DDIM / 128), 512, 0, stream>>>(
      Hpk, B2pk, (void*)out, b2, wgt);
}

// Round 15
// 1541.551 us; speedup vs baseline: 1.2088x; 1.2088x over previous
//
#include <hip/hip_runtime.h>
#include <hip/hip_bf16.h>
#include <math.h>

typedef __bf16 bf16_t;
typedef __bf16 bf16x4 __attribute__((ext_vector_type(4)));
typedef __bf16 bf16x8 __attribute__((ext_vector_type(8)));
typedef float  f32x4  __attribute__((ext_vector_type(4)));

#define AS1 __attribute__((address_space(1)))
#define AS3 __attribute__((address_space(3)))

__device__ __forceinline__ void gload_lds16(const bf16_t* g, char* l) {
  __builtin_amdgcn_global_load_lds((const AS1 void*)g, (AS3 void*)l, 16, 0, 0);
}

static constexpr int N_ROWS = 8192;
static constexpr int DDIM   = 4096;
static constexpr int KEXP   = 8;
static constexpr int FHID   = 1024;
static constexpr int KD     = 8192;     // inner dim of both GEMMs (2D and K*F)
static constexpr int NKT32  = KD / 32;  // 256 GEMM k-steps

// ============ packed 32-k-granular fragment-major format (v15) ============
// A: per (256-row panel, 32-k tile) 16 KB contiguous, byte layout == GEMM LDS A region:
//   off(R,k) = (R>>7)*8192 + ((k>>4)&1)*4096 + ((R>>5)&3)*1024 + ((k>>3)&1)*512
//            + (R&31)*16 + (k&7)*2                       [R in 0..255, k in 0..31]
// B: per (256-col panel, 32-k tile) 16 KB contiguous:
//   off(C,k) = ((k>>4)&1)*8192 + ((C>>5)&7)*1024 + ((k>>3)&1)*512 + (C&31)*16 + (k&7)*2
// Uniform tile stride 16384 -> GEMM staging pointers advance by +16384/tile (no
// modular, no multiply). Panel stride = NKT32*16384 = 4 MB.

// ---------------- routing: weights = softmax(h_mask @ Wr^T + br) ----------------
__global__ __launch_bounds__(256)
void routing_kernel(const float* __restrict__ hm, const float* __restrict__ Wr,
                    const float* __restrict__ br, float* __restrict__ wgt) {
  const int n = blockIdx.x;
  const int t = threadIdx.x;
  const int wid = t >> 6;
  const float4* row = (const float4*)(hm + (size_t)n * DDIM);
  float4 x[4];
#pragma unroll
  for (int j = 0; j < 4; ++j) x[j] = row[t + j * 256];
  __shared__ float red[KEXP][4];
  float part[KEXP];
#pragma unroll
  for (int k = 0; k < KEXP; ++k) {
    const float4* wr = (const float4*)(Wr + (size_t)k * DDIM);
    float s = 0.f;
#pragma unroll
    for (int j = 0; j < 4; ++j) {
      float4 w4 = wr[t + j * 256];
      s += x[j].x * w4.x + x[j].y * w4.y + x[j].z * w4.z + x[j].w * w4.w;
    }
#pragma unroll
    for (int off = 32; off > 0; off >>= 1) s += __shfl_down(s, off);
    part[k] = s;
  }
  if ((t & 63) == 0) {
#pragma unroll
    for (int k = 0; k < KEXP; ++k) red[k][wid] = part[k];
  }
  __syncthreads();
  if (t == 0) {
    float lg[KEXP];
    float mx = -1e30f;
#pragma unroll
    for (int k = 0; k < KEXP; ++k) {
      lg[k] = red[k][0] + red[k][1] + red[k][2] + red[k][3] + br[k];
      mx = fmaxf(mx, lg[k]);
    }
    float sum = 0.f;
#pragma unroll
    for (int k = 0; k < KEXP; ++k) { lg[k] = expf(lg[k] - mx); sum += lg[k]; }
    float inv = 1.f / sum;
#pragma unroll
    for (int k = 0; k < KEXP; ++k) wgt[(size_t)n * KEXP + k] = lg[k] * inv;
  }
}

// ---------------- pack kernels: fp32 source -> bf16 packed tiles (v15 layout) --------
__device__ __forceinline__ bf16x4 cvt4(float4 v) {
  bf16x4 o;
  o[0] = (bf16_t)v.x; o[1] = (bf16_t)v.y; o[2] = (bf16_t)v.z; o[3] = (bf16_t)v.w;
  return o;
}

__global__ __launch_bounds__(256)
void pack_cond_kernel(const float* __restrict__ ha, const float* __restrict__ hm,
                      bf16_t* __restrict__ Apk) {
  const int bm = blockIdx.x >> 7, t = blockIdx.x & 127;  // t = 64-k group (2 tiles)
  const int tid = threadIdx.x;
  const float* src = (t < 64) ? ha : hm;
  const int cb = (t & 63) * 64;
  __shared__ char pb[32768];
#pragma unroll
  for (int i = 0; i < 16; ++i) {
    int u = i * 256 + tid;
    int r = u >> 4, c = (u & 15) * 4;
    float4 v = *(const float4*)(src + (size_t)(bm * 256 + r) * DDIM + cb + c);
    int off = (c >> 5) * 16384 + ((r >> 7) & 1) * 8192 + ((c >> 4) & 1) * 4096
            + ((r >> 5) & 3) * 1024 + ((c >> 3) & 1) * 512 + (r & 31) * 16 + (c & 7) * 2;
    *(bf16x4*)(pb + off) = cvt4(v);
  }
  __syncthreads();
  char* dst = (char*)Apk + (size_t)blockIdx.x * 32768;
#pragma unroll
  for (int i = 0; i < 8; ++i) {
    int off = i * 4096 + tid * 16;
    *(float4*)(dst + off) = *(const float4*)(pb + off);
  }
}

__global__ __launch_bounds__(256)
void pack_w1_kernel(const float* __restrict__ W1, bf16_t* __restrict__ Bpk) {
  const int bn = blockIdx.x >> 7, t = blockIdx.x & 127;
  const int tid = threadIdx.x;
  __shared__ char pb[32768];
#pragma unroll
  for (int i = 0; i < 16; ++i) {
    int u = i * 256 + tid;
    int r = u >> 4, c = (u & 15) * 4;   // r = output col C, c = k local
    float4 v = *(const float4*)(W1 + (size_t)(bn * 256 + r) * KD + t * 64 + c);
    int off = (c >> 5) * 16384 + ((c >> 4) & 1) * 8192 + ((r >> 5) & 7) * 1024
            + ((c >> 3) & 1) * 512 + (r & 31) * 16 + (c & 7) * 2;
    *(bf16x4*)(pb + off) = cvt4(v);
  }
  __syncthreads();
  char* dst = (char*)Bpk + (size_t)blockIdx.x * 32768;
#pragma unroll
  for (int i = 0; i < 8; ++i) {
    int off = i * 4096 + tid * 16;
    *(float4*)(dst + off) = *(const float4*)(pb + off);
  }
}

__global__ __launch_bounds__(256)
void pack_w2_kernel(const float* __restrict__ W2, bf16_t* __restrict__ Bpk) {
  const int bn = blockIdx.x >> 7, t = blockIdx.x & 127;
  const int tid = threadIdx.x;
  const int ke = t >> 4, f0 = (t & 15) * 64;
  __shared__ char pb[32768];
#pragma unroll
  for (int i = 0; i < 16; ++i) {
    int u = i * 256 + tid;
    int r = u >> 4, c = (u & 15) * 4;
    float4 v = *(const float4*)(W2 + ((size_t)ke * DDIM + bn * 256 + r) * FHID + f0 + c);
    int off = (c >> 5) * 16384 + ((c >> 4) & 1) * 8192 + ((r >> 5) & 7) * 1024
            + ((c >> 3) & 1) * 512 + (r & 31) * 16 + (c & 7) * 2;
    *(bf16x4*)(pb + off) = cvt4(v);
  }
  __syncthreads();
  char* dst = (char*)Bpk + (size_t)blockIdx.x * 32768;
#pragma unroll
  for (int i = 0; i < 8; ++i) {
    int off = i * 4096 + tid * 16;
    *(float4*)(dst + off) = *(const float4*)(pb + off);
  }
}

// ---------------- GEMM v15: r13 structure + free addressing ----------------
// r13 (committed): BM=256 BN=128 BK=32, 3-buffer ring x 24KB = 72KB -> 2 blocks/CU
// (independent barriers de-lockstep MFMA vs LDS; MfmaUtil 55->61), 8 waves of 64x64,
// 16x16x32 MFMA, lgkm countdown(3/2/1/0) x 4-MFMA clusters, vmcnt(3) + ONE barrier
// per k-tile. v15 changes ONLY addressing cost:
//  - 32-k packed tiles -> staging pointers advance +16384/body (2 adds), no modular.
//    Tail overruns 2 tiles into adjacent mapped ws regions; staged bytes land in LDS
//    slots never read again (audited; deterministic).
//  - ring unrolled x3 (85 iters x 3 bodies + 1 tail body): buffer offsets are
//    compile-time -> every ds_read is base + immediate offset (zero VALU).
// MODE 1: +b1, exact GELU, *w[n][expert], store bf16 PACKED (Hpk = GEMM2's A)
// MODE 2: + sum_k w[n][k]*b2[k][col], store fp32 row-major (out)
template <int MODE, int NCOLS>
__global__ __launch_bounds__(512, 4)
void gemm_kernel(const bf16_t* __restrict__ Apk, const bf16_t* __restrict__ Bpk,
                 void* __restrict__ Cout, const float* __restrict__ bias,
                 const float* __restrict__ wgt) {
  __shared__ char lds[3 * 24576];        // 72 KB

  const int tid  = threadIdx.x;
  const int wid  = tid >> 6;             // 0..7
  const int lane = tid & 63;
  const int wr   = wid >> 1;             // 0..3  (M quarter, 64 rows)
  const int wc   = wid & 1;              // 0..1  (N half, 64 cols)

  // ---- 2-D concurrency-window block remap (16bm x 16bn window, 4x8 per XCD)
  constexpr int NBN    = NCOLS / 128;    // 64 (GEMM1) or 32 (GEMM2)
  constexpr int NWIN_N = NBN / 16;       // 4 or 2
  const int bid = blockIdx.x;
  const int w   = bid >> 8;
  const int sl  = bid & 255;
  const int xcd = sl & 7;
  const int cu  = sl >> 3;
  const int wm  = w / NWIN_N, wn = w % NWIN_N;
  const int bm  = wm * 16 + ((xcd >> 1) << 2) + (cu & 3);
  const int bn  = wn * 16 + ((xcd & 1) << 3) + (cu >> 2);
  const int arow0 = bm * 256;
  const int bcol0 = bn * 128;

  // ---- rolling staging pointers (per-thread, advance +16384/body)
  const int pA0 = 2 * wid, qB = wid;
  const char* pA = (const char*)Apk + (size_t)bm * NKT32 * 16384
                 + pA0 * 1024 + lane * 16;
  const char* pB = (const char*)Bpk + (size_t)(bn >> 1) * NKT32 * 16384
                 + (qB >> 2) * 8192 + ((bn & 1) * 4 + (qB & 3)) * 1024 + lane * 16;
  // LDS dst constants (wave-uniform + const): A piece -> p*1024, B piece -> 16384+q*1024
  const int dA = pA0 * 1024;
  const int dB = 16384 + qB * 1024;

  // ---- per-thread ds_read bases (all reads = base + compile-time immediate)
  const int lpart = (lane & 15) * 16 + ((lane >> 4) & 1) * 512 + (lane >> 5) * 4096;
  const char* pAr = lds + (wr >> 1) * 8192 + (wr & 1) * 2048 + lpart;
  const char* pBr = lds + 16384 + wc * 2048 + lpart;

  f32x4 acc[4][4];
  f32x4 zero = {0.f, 0.f, 0.f, 0.f};
#pragma unroll
  for (int mi = 0; mi < 4; ++mi)
#pragma unroll
    for (int nj = 0; nj < 4; ++nj) acc[mi][nj] = zero;

#define SB __builtin_amdgcn_sched_barrier(0);
#define STG(SBOFF)                                                               \
  gload_lds16((const bf16_t*)pA,          lds + (SBOFF) + dA);                   \
  gload_lds16((const bf16_t*)(pA + 1024), lds + (SBOFF) + dA + 1024);            \
  gload_lds16((const bf16_t*)pB,          lds + (SBOFF) + dB);                   \
  pA += 16384; pB += 16384;

#define BODY(RB, SBOFF)                                                          \
  {                                                                              \
    STG(SBOFF) SB                                                                \
    bf16x8 a0, a1, a2, a3, b0, b1, b2, b3;                                       \
    a0 = *(const bf16x8*)(pAr + (RB));          SB                               \
    a1 = *(const bf16x8*)(pAr + (RB) + 256);    SB                               \
    a2 = *(const bf16x8*)(pAr + (RB) + 1024);   SB                               \
    a3 = *(const bf16x8*)(pAr + (RB) + 1280);   SB                               \
    b0 = *(const bf16x8*)(pBr + (RB));          SB                               \
    b1 = *(const bf16x8*)(pBr + (RB) + 256);    SB                               \
    b2 = *(const bf16x8*)(pBr + (RB) + 1024);   SB                               \
    b3 = *(const bf16x8*)(pBr + (RB) + 1280);   SB                               \
    __builtin_amdgcn_s_setprio(1);                                               \
    asm volatile("s_waitcnt lgkmcnt(3)" ::: "memory"); SB                        \
    acc[0][0] = __builtin_amdgcn_mfma_f32_16x16x32_bf16(a0, b0, acc[0][0], 0, 0, 0); \
    acc[1][0] = __builtin_amdgcn_mfma_f32_16x16x32_bf16(a1, b0, acc[1][0], 0, 0, 0); \
    acc[2][0] = __builtin_amdgcn_mfma_f32_16x16x32_bf16(a2, b0, acc[2][0], 0, 0, 0); \
    acc[3][0] = __builtin_amdgcn_mfma_f32_16x16x32_bf16(a3, b0, acc[3][0], 0, 0, 0); \
    SB                                                                           \
    asm volatile("s_waitcnt lgkmcnt(2)" ::: "memory"); SB                        \
    acc[0][1] = __builtin_amdgcn_mfma_f32_16x16x32_bf16(a0, b1, acc[0][1], 0, 0, 0); \
    acc[1][1] = __builtin_amdgcn_mfma_f32_16x16x32_bf16(a1, b1, acc[1][1], 0, 0, 0); \
    acc[2][1] = __builtin_amdgcn_mfma_f32_16x16x32_bf16(a2, b1, acc[2][1], 0, 0, 0); \
    acc[3][1] = __builtin_amdgcn_mfma_f32_16x16x32_bf16(a3, b1, acc[3][1], 0, 0, 0); \
    SB                                                                           \
    asm volatile("s_waitcnt lgkmcnt(1)" ::: "memory"); SB                        \
    acc[0][2] = __builtin_amdgcn_mfma_f32_16x16x32_bf16(a0, b2, acc[0][2], 0, 0, 0); \
    acc[1][2] = __builtin_amdgcn_mfma_f32_16x16x32_bf16(a1, b2, acc[1][2], 0, 0, 0); \
    acc[2][2] = __builtin_amdgcn_mfma_f32_16x16x32_bf16(a2, b2, acc[2][2], 0, 0, 0); \
    acc[3][2] = __builtin_amdgcn_mfma_f32_16x16x32_bf16(a3, b2, acc[3][2], 0, 0, 0); \
    SB                                                                           \
    asm volatile("s_waitcnt lgkmcnt(0)" ::: "memory"); SB                        \
    acc[0][3] = __builtin_amdgcn_mfma_f32_16x16x32_bf16(a0, b3, acc[0][3], 0, 0, 0); \
    acc[1][3] = __builtin_amdgcn_mfma_f32_16x16x32_bf16(a1, b3, acc[1][3], 0, 0, 0); \
    acc[2][3] = __builtin_amdgcn_mfma_f32_16x16x32_bf16(a2, b3, acc[2][3], 0, 0, 0); \
    acc[3][3] = __builtin_amdgcn_mfma_f32_16x16x32_bf16(a3, b3, acc[3][3], 0, 0, 0); \
    SB                                                                           \
    __builtin_amdgcn_s_setprio(0);                                               \
    asm volatile("s_waitcnt vmcnt(3)" ::: "memory");                             \
    SB                                                                           \
    __builtin_amdgcn_s_barrier();                                                \
    SB                                                                           \
  }

  // ---- prologue: stage tile 0 -> buf0, tile 1 -> buf1; retire t0; barrier
  STG(0) STG(24576) SB
  asm volatile("s_waitcnt vmcnt(3)" ::: "memory");
  SB
  __builtin_amdgcn_s_barrier();
  SB

  // 256 tiles = 85 x {buf0,buf1,buf2} + 1 tail (t=255 -> buf0)
#pragma unroll 1
  for (int it = 0; it < 85; ++it) {
    BODY(0,     49152)
    BODY(24576, 0)
    BODY(49152, 24576)
  }
  BODY(0, 49152)
#undef BODY
#undef STG
#undef SB

  // ---- epilogue.  16x16 C/D layout: col = lane&15, row = (lane>>4)*4 + r  [m89/m91]
  const int rbase = arow0 + wr * 64 + ((lane >> 4) << 2);
  const int cbase = bcol0 + wc * 64 + (lane & 15);

  if constexpr (MODE == 1) {
    // packed H write (v15 A-format)
    char* __restrict__ Hc = (char*)Cout;
    const int kexp = bcol0 >> 10;  // expert is block-uniform (128 | 1024)
    float bv[4];
    size_t cpart[4];
#pragma unroll
    for (int nj = 0; nj < 4; ++nj) {
      int c = cbase + nj * 16;
      bv[nj] = bias[c];
      cpart[nj] = (size_t)(c >> 5) * 16384 + ((c >> 4) & 1) * 4096
                + ((c >> 3) & 1) * 512 + (c & 7) * 2;
    }
#pragma unroll
    for (int mi = 0; mi < 4; ++mi)
#pragma unroll
      for (int r = 0; r < 4; ++r) {
        int n = rbase + mi * 16 + r;
        float wn4 = wgt[(size_t)n * KEXP + kexp];
        size_t npart = (size_t)(n >> 8) * (NKT32 * 16384) + ((n >> 7) & 1) * 8192
                     + ((n >> 5) & 3) * 1024 + (n & 31) * 16;
#pragma unroll
        for (int nj = 0; nj < 4; ++nj) {
          float x = acc[mi][nj][r] + bv[nj];
          float g = 0.5f * x * (1.f + erff(x * 0.70710678118654752f));  // exact GELU
          *(bf16_t*)(Hc + npart + cpart[nj]) = (bf16_t)(g * wn4);
        }
      }
  } else {
    float* __restrict__ O = (float*)Cout;
    float bc[4][KEXP];
#pragma unroll
    for (int nj = 0; nj < 4; ++nj)
#pragma unroll
      for (int k = 0; k < KEXP; ++k)
        bc[nj][k] = bias[(size_t)k * NCOLS + cbase + nj * 16];
#pragma unroll
    for (int mi = 0; mi < 4; ++mi)
#pragma unroll
      for (int r = 0; r < 4; ++r) {
        int n = rbase + mi * 16 + r;
        const float4* wp = (const float4*)(wgt + (size_t)n * KEXP);
        float4 wa = wp[0], wb = wp[1];
        float w8[KEXP] = {wa.x, wa.y, wa.z, wa.w, wb.x, wb.y, wb.z, wb.w};
#pragma unroll
        for (int nj = 0; nj < 4; ++nj) {
          float s = 0.f;
#pragma unroll
          for (int k = 0; k < KEXP; ++k) s += w8[k] * bc[nj][k];
          O[(size_t)n * NCOLS + cbase + nj * 16] = acc[mi][nj][r] + s;
        }
      }
  }
}

extern "C" void kernel_launch(void* const* d_in, const int* in_sizes, int n_in,
                              void* d_out, int out_size, void* d_ws, size_t ws_size,
                              hipStream_t stream) {
  const float* h_anchor = (const float*)d_in[0];
  const float* h_mask   = (const float*)d_in[1];
  const float* Wr       = (const float*)d_in[2];
  const float* br       = (const float*)d_in[3];
  const float* W1       = (const float*)d_in[4];
  const float* b1       = (const float*)d_in[5];
  const float* W2       = (const float*)d_in[6];
  const float* b2       = (const float*)d_in[7];
  float* out = (float*)d_out;

  char* ws = (char*)d_ws;
  bf16_t* Apk  = (bf16_t*)(ws);                       // packed A    128 MB
  bf16_t* B1pk = (bf16_t*)(ws + ((size_t)128 << 20)); // packed W1   128 MB
  bf16_t* B2pk = (bf16_t*)(ws + ((size_t)256 << 20)); // packed W2    64 MB
  bf16_t* Hpk  = (bf16_t*)(ws + ((size_t)320 << 20)); // packed H1s  128 MB
  float*  wgt  = (float*) (ws + ((size_t)448 << 20)); // [8192][8]   256 KB

  routing_kernel<<<N_ROWS, 256, 0, stream>>>(h_mask, Wr, br, wgt);
  pack_cond_kernel<<<32 * 128, 256, 0, stream>>>(h_anchor, h_mask, Apk);
  pack_w1_kernel<<<32 * 128, 256, 0, stream>>>(W1, B1pk);
  pack_w2_kernel<<<16 * 128, 256, 0, stream>>>(W2, B2pk);

  gemm_kernel<1, 8192><<<(N_ROWS / 256) * (KD / 128), 512, 0, stream>>>(
      Apk, B1pk, (void*)Hpk, b1, wgt);
  gemm_kernel<2, 4096><<<(N_ROWS / 256) * (DDIM / 128), 512, 0, stream>>>(
      Hpk, B2pk, (void*)out, b2, wgt);
}